// Round 3
// baseline (102.046 us; speedup 1.0000x reference)
//
#include <hip/hip_runtime.h>
#include <hip/hip_bf16.h>

#define BIGF 1e30f

constexpr int T   = 128;    // trajectory points
constexpr int NB  = 16;     // roads
constexpr int NP  = 256;    // points per road
constexpr int NS  = NP - 1; // segments per branch (255)
constexpr int NB2 = 2 * NB; // fw + bw branches (32)

struct Smem {
  float Px[NP], Py[NP], Pz[NP];   // branch points (possibly reversed)
  float sl[NS];                   // segment lengths (0 if invalid)
  float t0[NS];                   // p0 projection parameter per segment
  float cum[NP];                  // cumulative arc length, cum[0]=0
  float qx[T], qy[T], qz[T];      // trajectory
  float tcum[T];                  // trajectory cumulative length
  unsigned char pmask[NP];        // point mask
  unsigned char segm[NS];         // segment mask
  float redf[4];
  int   redi[4];
  float entry_s;
  float total_s;
  int   max_valid_j;
  int   anyseg;
  int   best_b2;
  int   has_branch;
  int   traj_f32;
  int   rp_f32;
};

// ---- float dtype sniffing (defensive): a bf16 view of genuine data (|v| < ~100)
// has exponent <= ~0x86 everywhere; a bf16 view of an f32 buffer has random
// mantissa bits at even u16 indices -> 'bad' exponents w.p. ~0.46/elem. ----
__device__ __forceinline__ void sniff_f32_flags(const void* traj, const void* rp, Smem& s) {
  int tid = threadIdx.x;
  if (tid < 64) {
    unsigned short v = ((const unsigned short*)traj)[tid];
    int bad = ((v >> 7) & 0xFF) > 137;          // |v| >= ~1024, or inf/nan
    unsigned long long m = __ballot(bad);
    if (tid == 0) s.traj_f32 = (m != 0ull);
  } else if (tid < 128) {
    unsigned short v = ((const unsigned short*)rp)[tid - 64];
    int bad = ((v >> 7) & 0xFF) > 137;
    unsigned long long m = __ballot(bad);
    if (tid == 64) s.rp_f32 = (m != 0ull);
  }
}

__device__ __forceinline__ float loadv(const void* p, int is_f32, int idx) {
  return is_f32 ? ((const float*)p)[idx]
                : __bfloat162float(((const __hip_bfloat16*)p)[idx]);
}

// ---- mask dtype sniffing: lengths >= 2 guarantees mask[0,0,0]=mask[0,0,1]=true ----
__device__ __forceinline__ int sniff_mask_kind(const void* rm) {
  const unsigned char* u = (const unsigned char*)rm;
  unsigned char b0 = u[0], b1 = u[1], b4 = u[4];
  if (b0 == 1 && b1 == 1) return 0;                  // u8 / bool
  if (b0 == 1 && b1 == 0) return (b4 == 1) ? 1 : 2;  // i32 : i64
  if (b0 == 0) return 4;                             // f32
  return 3;                                          // bf16
}

__device__ __forceinline__ bool read_mask(const void* rm, int kind, int idx) {
  switch (kind) {
    case 0:  return ((const unsigned char*)rm)[idx] != 0;
    case 1:  return ((const int*)rm)[idx] != 0;
    case 2:  return ((const long long*)rm)[idx] != 0;
    case 3:  { unsigned short v = ((const unsigned short*)rm)[idx];
               return (unsigned short)(v << 1) != 0; }
    default: return ((const float*)rm)[idx] != 0.0f;
  }
}

// Full per-branch pipeline. WRITE_OUT=0: write cost to cost_ws. WRITE_OUT=1: write proj to out.
template <int WRITE_OUT>
__device__ void process_branch(Smem& s, int n, int b2,
                               const void* rp, const void* rm, int mkind,
                               const void* traj, int tf32, int rf32,
                               float* cost_ws, float* out) {
  const int tid = threadIdx.x;
  const int r   = b2 & (NB - 1);
  const int rev = b2 >> 4;

  // --- stage trajectory ---
  if (tid < T) {
    int base = (n * T + tid) * 3;
    s.qx[tid] = loadv(traj, tf32, base + 0);
    s.qy[tid] = loadv(traj, tf32, base + 1);
    s.qz[tid] = loadv(traj, tf32, base + 2);
  }
  // --- stage branch points (reversed for backward branches) + mask ---
  {
    int k = rev ? (NP - 1 - tid) : tid;
    int midx  = (n * NB + r) * NP + k;
    int pbase = midx * 3;
    s.Px[tid] = loadv(rp, rf32, pbase + 0);
    s.Py[tid] = loadv(rp, rf32, pbase + 1);
    s.Pz[tid] = loadv(rp, rf32, pbase + 2);
    s.pmask[tid] = read_mask(rm, mkind, midx) ? 1 : 0;
  }
  __syncthreads();

  // --- per-segment data + p0 projection candidates ---
  float d2 = BIGF;
  int   idx = tid;
  if (tid < NS) {
    float ax = s.Px[tid], ay = s.Py[tid], az = s.Pz[tid];
    float svx = s.Px[tid + 1] - ax, svy = s.Py[tid + 1] - ay, svz = s.Pz[tid + 1] - az;
    int smf = s.pmask[tid] & s.pmask[tid + 1];
    float svd2 = svx * svx + svy * svy + svz * svz;
    s.sl[tid]   = smf ? sqrtf(svd2) : 0.0f;
    s.segm[tid] = (unsigned char)smf;
    float px = s.qx[0], py = s.qy[0], pz = s.qz[0];
    float dx = px - ax, dy = py - ay, dz = pz - az;
    float svd = fmaxf(svd2, 1e-12f);
    float t0v = fminf(fmaxf((dx * svx + dy * svy + dz * svz) / svd, 0.0f), 1.0f);
    float qx0 = ax + t0v * svx, qy0 = ay + t0v * svy, qz0 = az + t0v * svz;
    float ex = px - qx0, ey = py - qy0, ez = pz - qz0;
    d2 = smf ? (ex * ex + ey * ey + ez * ez) : BIGF;
    s.t0[tid] = t0v;
  }
  __syncthreads();

  // --- wave-level argmin (first-min tie break) over all 256 candidates ---
  for (int off = 32; off; off >>= 1) {
    float od = __shfl_xor(d2, off, 64);
    int   oi = __shfl_xor(idx, off, 64);
    if (od < d2 || (od == d2 && oi < idx)) { d2 = od; idx = oi; }
  }
  if ((tid & 63) == 0) { s.redf[tid >> 6] = d2; s.redi[tid >> 6] = idx; }

  // --- divergent serial scans (different waves run concurrently) ---
  if (tid == 0) {
    float c = 0.0f;
    s.cum[0] = 0.0f;
    for (int p = 0; p < NS; ++p) { c += s.sl[p]; s.cum[p + 1] = c; }
    s.total_s = c;
  } else if (tid == 64) {
    float c = 0.0f;
    s.tcum[0] = 0.0f;
    for (int t = 0; t < T - 1; ++t) {
      float dx = s.qx[t + 1] - s.qx[t];
      float dy = s.qy[t + 1] - s.qy[t];
      float dz = s.qz[t + 1] - s.qz[t];
      c += sqrtf(dx * dx + dy * dy + dz * dz);
      s.tcum[t + 1] = c;
    }
  } else if (tid == 128) {
    int mj = 0, any = 0;
    for (int p = 0; p < NS; ++p)
      if (s.segm[p]) { any = 1; mj = p; }
    s.max_valid_j = mj;
    s.anyseg = any;
  }
  __syncthreads();

  if (tid == 0) {
    float bd = s.redf[0]; int bi = s.redi[0];
    for (int w = 1; w < 4; ++w) {
      if (s.redf[w] < bd || (s.redf[w] == bd && s.redi[w] < bi)) { bd = s.redf[w]; bi = s.redi[w]; }
    }
    s.entry_s = s.cum[bi] + s.t0[bi] * s.sl[bi];
  }
  __syncthreads();

  // --- per-trajectory-point projection ---
  float dist = 0.0f;
  if (tid < T) {
    float target = s.entry_s + s.tcum[tid];
    target = fminf(target, s.total_s);
    target = fmaxf(target, 0.0f);
    // upper_bound over cum[0..NP-1]; j = count(cum <= target) - 1
    int lo = 0, hi = NP;
    while (lo < hi) {
      int mid = (lo + hi) >> 1;
      if (s.cum[mid] <= target) lo = mid + 1; else hi = mid;
    }
    int j = lo - 1;
    if (j < 0) j = 0;
    int mvj = s.max_valid_j;
    if (j > mvj) j = mvj;
    float tl = (target - s.cum[j]) / fmaxf(s.sl[j], 1e-9f);
    tl = fminf(fmaxf(tl, 0.0f), 1.0f);
    float ax = s.Px[j], ay = s.Py[j], az = s.Pz[j];
    float prx = ax + tl * (s.Px[j + 1] - ax);
    float pry = ay + tl * (s.Py[j + 1] - ay);
    float prz = az + tl * (s.Pz[j + 1] - az);
    if (WRITE_OUT) {
      int ob = (n * T + tid) * 3;
      out[ob + 0] = prx;     // reference output dtype is float32
      out[ob + 1] = pry;
      out[ob + 2] = prz;
    } else {
      float dx = s.qx[tid] - prx, dy = s.qy[tid] - pry, dz = s.qz[tid] - prz;
      dist = sqrtf(dx * dx + dy * dy + dz * dz);
    }
  }

  if (!WRITE_OUT) {
    for (int off = 32; off; off >>= 1) dist += __shfl_xor(dist, off, 64);
    if ((tid & 63) == 0) s.redf[tid >> 6] = dist;
    __syncthreads();
    if (tid == 0) {
      float c = s.redf[0] + s.redf[1] + s.redf[2] + s.redf[3];
      cost_ws[n * NB2 + b2] = s.anyseg ? c : BIGF;
    }
  }
}

__global__ __launch_bounds__(256) void k1_costs(const void* rp, const void* rm,
                                                const void* traj, float* cost_ws) {
  __shared__ Smem s;
  int n  = (int)blockIdx.x >> 5;
  int b2 = (int)blockIdx.x & 31;
  int mkind = sniff_mask_kind(rm);
  sniff_f32_flags(traj, rp, s);
  __syncthreads();
  int tf32 = s.traj_f32, rf32 = s.rp_f32;
  process_branch<0>(s, n, b2, rp, rm, mkind, traj, tf32, rf32, cost_ws, nullptr);
}

__global__ __launch_bounds__(256) void k2_select(const void* rp, const void* rm,
                                                 const void* traj, const float* cost_ws,
                                                 float* out) {
  __shared__ Smem s;
  int n   = (int)blockIdx.x;
  int tid = threadIdx.x;
  int mkind = sniff_mask_kind(rm);
  sniff_f32_flags(traj, rp, s);
  if (tid == 0) {
    float best = BIGF; int bi = 0;
    for (int b = 0; b < NB2; ++b) {
      float c = cost_ws[n * NB2 + b];
      if (c < best) { best = c; bi = b; }  // strict < keeps first occurrence (numpy argmin)
    }
    s.best_b2 = bi;
    s.has_branch = (best < BIGF) ? 1 : 0;
  }
  __syncthreads();
  int tf32 = s.traj_f32, rf32 = s.rp_f32;
  if (s.has_branch) {
    process_branch<1>(s, n, s.best_b2, rp, rm, mkind, traj, tf32, rf32, nullptr, out);
  } else if (tid < T) {
    int ob = (n * T + tid) * 3;
    out[ob + 0] = loadv(traj, tf32, ob + 0);
    out[ob + 1] = loadv(traj, tf32, ob + 1);
    out[ob + 2] = loadv(traj, tf32, ob + 2);
  }
}

extern "C" void kernel_launch(void* const* d_in, const int* in_sizes, int n_in,
                              void* d_out, int out_size, void* d_ws, size_t ws_size,
                              hipStream_t stream) {
  const void* traj = d_in[0];   // (N,T,3) f32 (sniffed on device; bf16 fallback)
  const void* rp   = d_in[1];   // (N,NB,NP,3) f32 (sniffed; bf16 fallback)
  const void* rm   = d_in[2];   // (N,NB,NP) mask, dtype sniffed
  float* out = (float*)d_out;   // (N,T,3) f32 — reference output dtype
  float* cost_ws = (float*)d_ws; // N*32 floats

  int N = in_sizes[0] / (T * 3);

  k1_costs<<<dim3(N * NB2), dim3(256), 0, stream>>>(rp, rm, traj, cost_ws);
  k2_select<<<dim3(N), dim3(256), 0, stream>>>(rp, rm, traj, cost_ws, out);
}

// Round 4
// 70.102 us; speedup vs baseline: 1.4557x; 1.4557x over previous
//
#include <hip/hip_runtime.h>
#include <hip/hip_bf16.h>

#define BIGF 1e30f

constexpr int T   = 128;    // trajectory points
constexpr int NB  = 16;     // roads
constexpr int NP  = 256;    // points per road
constexpr int NS  = NP - 1; // segments per branch (255)
constexpr int NB2 = 2 * NB; // fw + bw branches (32)

struct Smem {
  float Px[NP], Py[NP], Pz[NP];   // branch points (possibly reversed)
  float sl[NS];                   // segment lengths (0 if invalid)
  float t0[NS];                   // p0 projection parameter per segment
  float cum[NP];                  // cumulative arc length, cum[0]=0
  float qx[T], qy[T], qz[T];      // trajectory
  float tcum[T];                  // trajectory cumulative length
  unsigned char pmask[NP];        // point mask
  unsigned long long wmask[4];    // per-wave segment-valid ballot
  float wsumA[4], wsumB[4];       // scan wave totals
  float argf[4]; int argi[4];     // argmin / dist-reduce scratch
  float entry_s, total_s;
  int   max_valid_j, anyseg;
  int   traj_f32, rp_f32;
};

// ---- float dtype sniffing (defensive): a bf16 view of genuine data (|v|<~100)
// has exponent <= ~0x86 everywhere; a bf16 view of an f32 buffer has random
// mantissa bits at even u16 indices -> 'bad' exponents w.p. ~0.46/elem. ----
__device__ __forceinline__ void sniff_f32_flags(const void* traj, const void* rp, Smem& s) {
  int tid = threadIdx.x;
  if (tid < 64) {
    unsigned short v = ((const unsigned short*)traj)[tid];
    unsigned long long m = __ballot(((v >> 7) & 0xFF) > 137);
    if (tid == 0) s.traj_f32 = (m != 0ull);
  } else if (tid < 128) {
    unsigned short v = ((const unsigned short*)rp)[tid - 64];
    unsigned long long m = __ballot(((v >> 7) & 0xFF) > 137);
    if (tid == 64) s.rp_f32 = (m != 0ull);
  }
}

__device__ __forceinline__ float loadv(const void* p, int is_f32, int idx) {
  return is_f32 ? ((const float*)p)[idx]
                : __bfloat162float(((const __hip_bfloat16*)p)[idx]);
}

// ---- mask dtype sniffing: lengths >= 2 guarantees mask[0,0,0]=mask[0,0,1]=true ----
__device__ __forceinline__ int sniff_mask_kind(const void* rm) {
  const unsigned char* u = (const unsigned char*)rm;
  unsigned char b0 = u[0], b1 = u[1], b4 = u[4];
  if (b0 == 1 && b1 == 1) return 0;                  // u8 / bool
  if (b0 == 1 && b1 == 0) return (b4 == 1) ? 1 : 2;  // i32 : i64
  if (b0 == 0) return 4;                             // f32
  return 3;                                          // bf16
}

__device__ __forceinline__ bool read_mask(const void* rm, int kind, int idx) {
  switch (kind) {
    case 0:  return ((const unsigned char*)rm)[idx] != 0;
    case 1:  return ((const int*)rm)[idx] != 0;
    case 2:  return ((const long long*)rm)[idx] != 0;
    case 3:  { unsigned short v = ((const unsigned short*)rm)[idx];
               return (unsigned short)(v << 1) != 0; }
    default: return ((const float*)rm)[idx] != 0.0f;
  }
}

// k1: one block per (n, branch2). Computes cost AND stores the projected points.
__global__ __launch_bounds__(256) void k1_costs(const void* rp, const void* rm,
                                                const void* traj,
                                                float* cost_ws, float* proj_ws) {
  __shared__ Smem s;
  const int tid  = threadIdx.x;
  const int lane = tid & 63;
  const int w    = tid >> 6;
  const int n    = (int)blockIdx.x >> 5;
  const int b2   = (int)blockIdx.x & 31;
  const int r    = b2 & (NB - 1);
  const int rev  = b2 >> 4;
  const int mkind = sniff_mask_kind(rm);

  sniff_f32_flags(traj, rp, s);
  __syncthreads();                              // B0: sniff flags visible
  const int tf32 = s.traj_f32, rf32 = s.rp_f32;

  // --- stage trajectory + branch points (reversed for bw) + mask ---
  if (tid < T) {
    int base = (n * T + tid) * 3;
    s.qx[tid] = loadv(traj, tf32, base + 0);
    s.qy[tid] = loadv(traj, tf32, base + 1);
    s.qz[tid] = loadv(traj, tf32, base + 2);
  }
  {
    int k = rev ? (NP - 1 - tid) : tid;
    int midx  = (n * NB + r) * NP + k;
    int pbase = midx * 3;
    s.Px[tid] = loadv(rp, rf32, pbase + 0);
    s.Py[tid] = loadv(rp, rf32, pbase + 1);
    s.Pz[tid] = loadv(rp, rf32, pbase + 2);
    s.pmask[tid] = read_mask(rm, mkind, midx) ? 1 : 0;
  }
  __syncthreads();                              // B1: staging complete

  // --- per-segment data + p0 projection candidate (registers) ---
  float d2 = BIGF;
  int   idx = tid;
  float slv = 0.0f;
  int   smf = 0;
  if (tid < NS) {
    float ax = s.Px[tid], ay = s.Py[tid], az = s.Pz[tid];
    float svx = s.Px[tid + 1] - ax, svy = s.Py[tid + 1] - ay, svz = s.Pz[tid + 1] - az;
    smf = s.pmask[tid] & s.pmask[tid + 1];
    float svd2 = svx * svx + svy * svy + svz * svz;
    slv = smf ? sqrtf(svd2) : 0.0f;
    s.sl[tid] = slv;
    float px = s.qx[0], py = s.qy[0], pz = s.qz[0];
    float dx = px - ax, dy = py - ay, dz = pz - az;
    float svd = fmaxf(svd2, 1e-12f);
    float t0v = fminf(fmaxf((dx * svx + dy * svy + dz * svz) / svd, 0.0f), 1.0f);
    s.t0[tid] = t0v;
    float qx0 = ax + t0v * svx, qy0 = ay + t0v * svy, qz0 = az + t0v * svz;
    float ex = px - qx0, ey = py - qy0, ez = pz - qz0;
    d2 = smf ? (ex * ex + ey * ey + ez * ez) : BIGF;
  }
  // per-wave valid-segment ballot (for max_valid_j / anyseg)
  {
    unsigned long long m = __ballot(smf != 0);
    if (lane == 0) s.wmask[w] = m;
  }
  // per-wave argmin (lexicographic (d2, idx) == numpy first-min)
  for (int off = 32; off; off >>= 1) {
    float od = __shfl_xor(d2, off, 64);
    int   oi = __shfl_xor(idx, off, 64);
    if (od < d2 || (od == d2 && oi < idx)) { d2 = od; idx = oi; }
  }
  if (lane == 0) { s.argf[w] = d2; s.argi[w] = idx; }

  // traj segment length (registers)
  float tlv = 0.0f;
  if (tid < T - 1) {
    float dx = s.qx[tid + 1] - s.qx[tid];
    float dy = s.qy[tid + 1] - s.qy[tid];
    float dz = s.qz[tid + 1] - s.qz[tid];
    tlv = sqrtf(dx * dx + dy * dy + dz * dz);
  }

  // --- fused parallel inclusive scan of (slv, tlv) via wave shuffles ---
  float xa = slv, xb = tlv;
  #pragma unroll
  for (int off = 1; off < 64; off <<= 1) {
    float ya = __shfl_up(xa, off, 64);
    float yb = __shfl_up(xb, off, 64);
    if (lane >= off) { xa += ya; xb += yb; }
  }
  if (lane == 63) { s.wsumA[w] = xa; s.wsumB[w] = xb; }
  __syncthreads();                              // B2: wave totals + sl/t0 visible
  {
    float pa = 0.0f, pb = 0.0f;
    if (w > 0) { pa += s.wsumA[0]; pb += s.wsumB[0]; }
    if (w > 1) { pa += s.wsumA[1]; pb += s.wsumB[1]; }
    if (w > 2) { pa += s.wsumA[2]; pb += s.wsumB[2]; }
    xa += pa; xb += pb;
  }
  if (tid < NS)    s.cum[tid + 1]  = xa;        // cum[1..255]
  if (tid < T - 1) s.tcum[tid + 1] = xb;        // tcum[1..127]
  if (tid == 255)  { s.cum[0] = 0.0f; s.tcum[0] = 0.0f; s.total_s = xa; }
  __syncthreads();                              // B3: cum/tcum ready

  if (tid == 0) {
    float bd = s.argf[0]; int bi = s.argi[0];
    #pragma unroll
    for (int ww = 1; ww < 4; ++ww)
      if (s.argf[ww] < bd || (s.argf[ww] == bd && s.argi[ww] < bi)) { bd = s.argf[ww]; bi = s.argi[ww]; }
    s.entry_s = s.cum[bi] + s.t0[bi] * s.sl[bi];
    int mj = 0, any = 0;
    #pragma unroll
    for (int ww = 3; ww >= 0; --ww) {
      unsigned long long m = s.wmask[ww];
      if (m) { any = 1; mj = ww * 64 + 63 - __clzll(m); break; }
    }
    s.max_valid_j = mj;
    s.anyseg = any;
  }
  __syncthreads();                              // B4: entry_s/max_valid_j ready

  // --- per-trajectory-point projection + store + distance ---
  float dist = 0.0f;
  if (tid < T) {
    float target = s.entry_s + s.tcum[tid];
    target = fminf(target, s.total_s);
    target = fmaxf(target, 0.0f);
    // j = count(cum <= target) - 1 over cum[0..NP-1]
    int lo = 0, hi = NP;
    while (lo < hi) {
      int mid = (lo + hi) >> 1;
      if (s.cum[mid] <= target) lo = mid + 1; else hi = mid;
    }
    int j = lo - 1;
    if (j < 0) j = 0;
    int mvj = s.max_valid_j;
    if (j > mvj) j = mvj;
    float tl = (target - s.cum[j]) / fmaxf(s.sl[j], 1e-9f);
    tl = fminf(fmaxf(tl, 0.0f), 1.0f);
    float ax = s.Px[j], ay = s.Py[j], az = s.Pz[j];
    float prx = ax + tl * (s.Px[j + 1] - ax);
    float pry = ay + tl * (s.Py[j + 1] - ay);
    float prz = az + tl * (s.Pz[j + 1] - az);
    int ob = ((n * NB2 + b2) * T + tid) * 3;
    proj_ws[ob + 0] = prx;
    proj_ws[ob + 1] = pry;
    proj_ws[ob + 2] = prz;
    float dx = s.qx[tid] - prx, dy = s.qy[tid] - pry, dz = s.qz[tid] - prz;
    dist = sqrtf(dx * dx + dy * dy + dz * dz);
  }
  for (int off = 32; off; off >>= 1) dist += __shfl_xor(dist, off, 64);
  if (lane == 0) s.argf[w] = dist;              // WAR over B4 — safe
  __syncthreads();                              // B5
  if (tid == 0) {
    float c = s.argf[0] + s.argf[1] + s.argf[2] + s.argf[3];
    cost_ws[n * NB2 + b2] = s.anyseg ? c : BIGF;
  }
}

// k2: one block per n — argmin over 32 costs, gather winning projection.
__global__ __launch_bounds__(128) void k2_select(const void* traj, const float* cost_ws,
                                                 const float* proj_ws, float* out) {
  __shared__ int sb[2];
  __shared__ int stf;
  const int n = (int)blockIdx.x;
  const int tid = threadIdx.x;
  if (tid < 64) {
    unsigned short v = ((const unsigned short*)traj)[tid];
    unsigned long long m = __ballot(((v >> 7) & 0xFF) > 137);
    if (tid == 0) stf = (m != 0ull);
  }
  if (tid == 0) {
    float best = BIGF; int bi = 0;
    #pragma unroll
    for (int b = 0; b < NB2; ++b) {
      float c = cost_ws[n * NB2 + b];
      if (c < best) { best = c; bi = b; }       // strict <: numpy first-min
    }
    sb[0] = bi;
    sb[1] = (best < BIGF) ? 1 : 0;
  }
  __syncthreads();
  int bi = sb[0], has = sb[1], tf = stf;
  int ob = (n * T + tid) * 3;
  if (has) {
    int ib = ((n * NB2 + bi) * T + tid) * 3;
    out[ob + 0] = proj_ws[ib + 0];
    out[ob + 1] = proj_ws[ib + 1];
    out[ob + 2] = proj_ws[ib + 2];
  } else {
    out[ob + 0] = loadv(traj, tf, ob + 0);
    out[ob + 1] = loadv(traj, tf, ob + 1);
    out[ob + 2] = loadv(traj, tf, ob + 2);
  }
}

extern "C" void kernel_launch(void* const* d_in, const int* in_sizes, int n_in,
                              void* d_out, int out_size, void* d_ws, size_t ws_size,
                              hipStream_t stream) {
  const void* traj = d_in[0];   // (N,T,3) f32 (sniffed on device; bf16 fallback)
  const void* rp   = d_in[1];   // (N,NB,NP,3) f32 (sniffed; bf16 fallback)
  const void* rm   = d_in[2];   // (N,NB,NP) mask, dtype sniffed
  float* out = (float*)d_out;   // (N,T,3) f32

  int N = in_sizes[0] / (T * 3);

  float* cost_ws = (float*)d_ws;                 // N*NB2 floats (8 KB)
  float* proj_ws = cost_ws + (size_t)N * NB2;    // N*NB2*T*3 floats (~3 MB)

  k1_costs<<<dim3(N * NB2), dim3(256), 0, stream>>>(rp, rm, traj, cost_ws, proj_ws);
  k2_select<<<dim3(N), dim3(128), 0, stream>>>(traj, cost_ws, proj_ws, out);
}